// Round 15
// baseline (207.960 us; speedup 1.0000x reference)
//
#include <hip/hip_runtime.h>

#define NN 4096
#define DIM 128
#define TN 32            // q-rows per block
#define TM 128           // m-tile size
#define NSPLIT 4         // split-m factor
#define NTILES 8         // tiles per block (32 global tiles / 4)

typedef __attribute__((ext_vector_type(8))) short bf16x8;
typedef __attribute__((ext_vector_type(4))) float f32x4;

#define LSTRIDE 136                    // ushorts per row (272 B, 16B-aligned)
#define REGION  (128 * LSTRIDE)        // Hrow region: 17408 ushorts = 34816 B
#define TILE_CHUNKS 34                 // 34816 / 1024
#define PST 136                        // P row stride (ushorts)

__device__ inline unsigned short f2bf(float x) {
    union { float f; unsigned u; } v; v.f = x;
    unsigned r = v.u + 0x7FFFu + ((v.u >> 16) & 1u);
    return (unsigned short)(r >> 16);
}

// async global->LDS DMA, 16 B/lane, dest = wave-uniform base + lane*16
__device__ inline void dma16(const void* g, void* l) {
    __builtin_amdgcn_global_load_lds(
        (const __attribute__((address_space(1))) void*)g,
        (__attribute__((address_space(3))) void*)l,
        16, 0, 0);
}

// ---- prep: hidden fp32 -> Hpack[32 tiles][Hrow 128x136] + hbt[DIM][NN] bf16 ----
__global__ __launch_bounds__(256) void prep_pack_kernel(
    const float* __restrict__ hidden,
    unsigned short* __restrict__ Hpack,
    unsigned short* __restrict__ hbt)
{
    __shared__ unsigned short T[128 * LSTRIDE];
    const int tid = threadIdx.x;
    const int t0  = blockIdx.x;        // tile 0..31
    const int m0  = t0 * TM;
    unsigned short* rowdst = Hpack + (size_t)t0 * REGION;

    #pragma unroll
    for (int it = 0; it < 16; ++it) {
        int idx = tid + 256 * it;      // 128 rows x 32 float4 chunks
        int row = idx >> 5;
        int c4  = (idx & 31) * 4;
        float4 v = *(const float4*)(hidden + (size_t)(m0 + row) * DIM + c4);
        ushort4 o;
        o.x = f2bf(v.x); o.y = f2bf(v.y); o.z = f2bf(v.z); o.w = f2bf(v.w);
        *(ushort4*)(rowdst + row * LSTRIDE + c4) = o;
        T[(c4 + 0) * LSTRIDE + row] = o.x;
        T[(c4 + 1) * LSTRIDE + row] = o.y;
        T[(c4 + 2) * LSTRIDE + row] = o.z;
        T[(c4 + 3) * LSTRIDE + row] = o.w;
    }
    __syncthreads();
    #pragma unroll
    for (int it = 0; it < 8; ++it) {
        int idx = tid + 256 * it;      // 128 d x 16 chunks of 8 ushorts
        int d  = idx >> 4;
        int c8 = (idx & 15) * 8;
        uint4 v = *(const uint4*)(T + d * LSTRIDE + c8);
        *(uint4*)(hbt + (size_t)d * NN + m0 + c8) = v;
    }
}

// ---- main: TN=32, Hrow-only LDS (2 blocks/CU), PV B-frags direct from hbt,
//      double-buffered DMA, lgkm-only mid barrier, direct adj loads ----
__global__ __launch_bounds__(512, 4) void gat_flash_kernel(
    const float* __restrict__ hidden,        // fp32 (Q only)
    const unsigned short* __restrict__ Hpack,// [32][REGION]
    const unsigned short* __restrict__ hbt,  // [DIM][NN] bf16 transposed
    const int*   __restrict__ adj,           // [NN][NN] int32
    const float* __restrict__ W,
    const float* __restrict__ bvec,
    float*       __restrict__ Opart,         // [512][TN][DIM]
    float*       __restrict__ lpart)         // [512][TN]
{
    __shared__ __align__(16) unsigned short HH[2][REGION];     // 69632 B
    __shared__ __align__(16) unsigned short Plc[TN * PST];     // 8704 B
    __shared__ float redsum[8][16];                            // 512 B

    const int tid  = threadIdx.x;
    const int w    = tid >> 6;
    const int lane = tid & 63;
    const int g    = lane >> 4;
    const int l15  = lane & 15;
    const int blk  = blockIdx.x;
    const int nb   = blk >> 2;         // 0..127 row-group of 32
    const int q4   = blk & 3;
    const int n0   = nb * TN;
    const int gt0  = q4 * NTILES;      // first global tile (of 32)
    const int rg   = w >> 2;           // 0/1: 16-row group
    const int ms   = w & 3;            // QK m-slice (32 wide) / PV d-quarter
    const int lofs = lane * 16;
    const float NEG = -9.0e15f;

    const float b0 = bvec[0], b1 = bvec[1], b2 = bvec[2], b3 = bvec[3];

    // ---- prologue: DMA tile 0 -> HH[0] (overlaps Q compute below) ----
    {
        const char* src = (const char*)(Hpack + (size_t)gt0 * REGION);
        char* dst = (char*)&HH[0][0];
        #pragma unroll
        for (int it = 0; it < 5; ++it) {
            int chunk = it * 8 + w;
            if (chunk < TILE_CHUNKS)
                dma16(src + chunk * 1024 + lofs, dst + chunk * 1024);
        }
    }
    // Q into HH[1] rows k*32+r (128 rows x 128 d == exactly REGION)
    {
        int qr = tid >> 2;             // 0..127 = k*32 + r
        int r  = qr & 31;
        int d0 = (tid & 3) * 32;
        const float* hrow = hidden + (size_t)(n0 + r) * DIM + d0;
        const float* wrow = W + (qr >> 5) * DIM + d0;
        unsigned short* qdst = &HH[1][qr * LSTRIDE + d0];
        #pragma unroll
        for (int c = 0; c < 8; ++c) {
            float4 hv = *(const float4*)(hrow + 4 * c);
            float4 wv = *(const float4*)(wrow + 4 * c);
            ushort4 o;
            o.x = f2bf(hv.x * wv.x); o.y = f2bf(hv.y * wv.y);
            o.z = f2bf(hv.z * wv.z); o.w = f2bf(hv.w * wv.w);
            *(ushort4*)(qdst + 4 * c) = o;
        }
    }
    __syncthreads();   // drains tile-0 DMA (vmcnt) + Q LDS writes (lgkm)

    // A-fragments for this wave's 16 rows; HH[1] becomes a staging buffer
    bf16x8 Af[4][4];
    #pragma unroll
    for (int k = 0; k < 4; ++k)
        #pragma unroll
        for (int ks = 0; ks < 4; ++ks)
            Af[k][ks] = *(const bf16x8*)&HH[1][(k * 32 + rg * 16 + l15) * LSTRIDE + ks * 32 + 8 * g];
    __syncthreads();   // Af reads drained before tile-1 DMA may write HH[1]

    float lrow[4] = {0.f, 0.f, 0.f, 0.f};
    f32x4 Oacc[2];
    Oacc[0] = (f32x4){0.f, 0.f, 0.f, 0.f};
    Oacc[1] = (f32x4){0.f, 0.f, 0.f, 0.f};

    // direct adj codes for tile 0: 8 coalesced int loads/lane
    const size_t arow = (size_t)(n0 + rg * 16 + 4 * g) * NN;   // row of t=0
    int avc[8], avn[8];
    #pragma unroll
    for (int ch = 0; ch < 2; ++ch)
        #pragma unroll
        for (int t = 0; t < 4; ++t)
            avc[ch * 4 + t] = adj[arow + (size_t)t * NN + gt0 * TM + ms * 32 + ch * 16 + l15];

    for (int tile = 0; tile < NTILES; ++tile) {
        const int cur = tile & 1;
        const int nxt = cur ^ 1;
        const int mt0 = (gt0 + tile) * TM;

        // ---- issue next-tile DMA + adj prefetch; stays in flight all tile ----
        if (tile + 1 < NTILES) {
            const char* src = (const char*)(Hpack + (size_t)(gt0 + tile + 1) * REGION);
            char* dst = (char*)&HH[nxt][0];
            #pragma unroll
            for (int it = 0; it < 5; ++it) {
                int chunk = it * 8 + w;
                if (chunk < TILE_CHUNKS)
                    dma16(src + chunk * 1024 + lofs, dst + chunk * 1024);
            }
            #pragma unroll
            for (int ch = 0; ch < 2; ++ch)
                #pragma unroll
                for (int t = 0; t < 4; ++t)
                    avn[ch * 4 + t] = adj[arow + (size_t)t * NN + (gt0 + tile + 1) * TM + ms * 32 + ch * 16 + l15];
        }

        // ---- QK: S[k][ch] over m-slice [ms*32, +32) for rows rg*16..+16 ----
        f32x4 S[4][2];
        #pragma unroll
        for (int k = 0; k < 4; ++k) {
            S[k][0] = (f32x4){0.f, 0.f, 0.f, 0.f};
            S[k][1] = (f32x4){0.f, 0.f, 0.f, 0.f};
        }
        #pragma unroll
        for (int ks = 0; ks < 4; ++ks) {
            #pragma unroll
            for (int ch = 0; ch < 2; ++ch) {
                bf16x8 B = *(const bf16x8*)&HH[cur][(ms * 32 + ch * 16 + l15) * LSTRIDE + ks * 32 + 8 * g];
                #pragma unroll
                for (int k = 0; k < 4; ++k)
                    S[k][ch] = __builtin_amdgcn_mfma_f32_16x16x32_bf16(Af[k][ks], B, S[k][ch], 0, 0, 0);
            }
        }

        // ---- select + leakyrelu + exp (no-max softmax; scores bounded) ----
        #pragma unroll
        for (int ch = 0; ch < 2; ++ch) {
            #pragma unroll
            for (int t = 0; t < 4; ++t) {
                int a = avc[ch * 4 + t];
                float s = S[0][ch][t] + b0;
                s = (a == 2) ? S[1][ch][t] + b1 : s;
                s = (a == 3) ? S[2][ch][t] + b2 : s;
                s = (a == 4) ? S[3][ch][t] + b3 : s;
                float e = fmaxf(s, 0.2f * s);
                e = (a == 0) ? NEG : e;
                float p = __expf(e);           // exp(-9e15) -> exactly 0
                lrow[t] += p;
                Plc[(rg * 16 + 4 * g + t) * PST + ms * 32 + ch * 16 + l15] = f2bf(p);
            }
        }

        // ---- P-ready barrier: LDS-only drain; DMA stays in flight ----
        asm volatile("s_waitcnt lgkmcnt(0)\n\ts_barrier" ::: "memory");

        // ---- PV: rows rg*16..+16, d-quarter [ms*32, +32), K=128;
        //      B-frags loaded directly from hbt (L2-resident) ----
        #pragma unroll
        for (int c4 = 0; c4 < 4; ++c4) {
            bf16x8 Pa = *(const bf16x8*)&Plc[(rg * 16 + l15) * PST + c4 * 32 + 8 * g];
            #pragma unroll
            for (int dt = 0; dt < 2; ++dt) {
                const unsigned short* hp = hbt + (size_t)(ms * 32 + dt * 16 + l15) * NN + mt0 + c4 * 32 + 8 * g;
                bf16x8 Bv = *(const bf16x8*)hp;
                Oacc[dt] = __builtin_amdgcn_mfma_f32_16x16x32_bf16(Pa, Bv, Oacc[dt], 0, 0, 0);
            }
        }

        #pragma unroll
        for (int i = 0; i < 8; ++i) avc[i] = avn[i];
        __syncthreads();   // vmcnt(0) drain == "HH[nxt] staged"; buffer swap
    }

    // ---- epilogue ----
    #pragma unroll
    for (int t = 0; t < 4; ++t) {
        float v = lrow[t];
        v += __shfl_xor(v, 1); v += __shfl_xor(v, 2);
        v += __shfl_xor(v, 4); v += __shfl_xor(v, 8);
        if (l15 == 0) redsum[w][4 * g + t] = v;
    }
    __syncthreads();
    if (tid < 32) {
        int rgp = tid >> 4, rr = tid & 15;
        float s = redsum[rgp * 4 + 0][rr] + redsum[rgp * 4 + 1][rr]
                + redsum[rgp * 4 + 2][rr] + redsum[rgp * 4 + 3][rr];
        lpart[blk * 32 + tid] = s;
    }
    float* Ob = Opart + (size_t)blk * TN * DIM;
    #pragma unroll
    for (int dt = 0; dt < 2; ++dt)
        #pragma unroll
        for (int t = 0; t < 4; ++t)
            Ob[(rg * 16 + 4 * g + t) * DIM + ms * 32 + dt * 16 + l15] = Oacc[dt][t];
}

// ---- combine the four m-quarters ----
__global__ __launch_bounds__(256) void combine_kernel(
    const float* __restrict__ Opart, const float* __restrict__ lpart,
    float* __restrict__ out)
{
    int idx = blockIdx.x * 256 + threadIdx.x;
    int r = idx >> 7, d = idx & 127;
    int nb = r >> 5, rr = r & 31;
    float O = 0.f, l = 0.f;
    #pragma unroll
    for (int q = 0; q < NSPLIT; ++q) {
        O += Opart[(size_t)(nb * NSPLIT + q) * (TN * DIM) + rr * 128 + d];
        l += lpart[(nb * NSPLIT + q) * 32 + rr];
    }
    out[idx] = O / l;
}

extern "C" void kernel_launch(void* const* d_in, const int* in_sizes, int n_in,
                              void* d_out, int out_size, void* d_ws, size_t ws_size,
                              hipStream_t stream) {
    const float* hidden = (const float*)d_in[0];
    const int*   adj    = (const int*)d_in[1];
    const float* W      = (const float*)d_in[2];
    const float* b      = (const float*)d_in[3];
    float* out = (float*)d_out;

    char* ws = (char*)d_ws;
    unsigned short* Hpack = (unsigned short*)ws;                 // 32*34816 = 1.09 MB
    unsigned short* hbt   = (unsigned short*)(ws + (2u << 20));  // 1 MB
    float* Opart = (float*)(ws + (4u << 20));                    // 512*32*128*4 = 8 MB
    float* lpart = (float*)(ws + (12u << 20));                   // 64 KB

    prep_pack_kernel<<<NN / TM, 256, 0, stream>>>(hidden, Hpack, hbt);
    gat_flash_kernel<<<512, 512, 0, stream>>>(hidden, Hpack, hbt, adj, W, b, Opart, lpart);
    combine_kernel<<<NN * DIM / 256, 256, 0, stream>>>(Opart, lpart, out);
}

// Round 16
// 160.459 us; speedup vs baseline: 1.2960x; 1.2960x over previous
//
#include <hip/hip_runtime.h>

#define NN 4096
#define DIM 128
#define TN 32            // q-rows per block
#define TM 128           // m-tile size
#define NSPLIT 4         // split-m factor
#define NTILES 8         // tiles per block (32 global tiles / 4)

typedef __attribute__((ext_vector_type(8))) short bf16x8;
typedef __attribute__((ext_vector_type(4))) float f32x4;

#define LSTRIDE 136                    // ushorts per row (272 B, 16B-aligned)
#define REGION  (128 * LSTRIDE)        // Hrow region: 17408 ushorts = 34816 B
#define TILE_CHUNKS 34                 // 34816 / 1024
#define PST 136                        // P row stride (ushorts)

__device__ inline unsigned short f2bf(float x) {
    union { float f; unsigned u; } v; v.f = x;
    unsigned r = v.u + 0x7FFFu + ((v.u >> 16) & 1u);
    return (unsigned short)(r >> 16);
}

// async global->LDS DMA, 16 B/lane, dest = wave-uniform base + lane*16
__device__ inline void dma16(const void* g, void* l) {
    __builtin_amdgcn_global_load_lds(
        (const __attribute__((address_space(1))) void*)g,
        (__attribute__((address_space(3))) void*)l,
        16, 0, 0);
}

// ---- prep: hidden fp32 -> Hpack[32 tiles][Hrow 128x136] + hbt[DIM][NN] bf16 ----
__global__ __launch_bounds__(256) void prep_pack_kernel(
    const float* __restrict__ hidden,
    unsigned short* __restrict__ Hpack,
    unsigned short* __restrict__ hbt)
{
    __shared__ unsigned short T[128 * LSTRIDE];
    const int tid = threadIdx.x;
    const int t0  = blockIdx.x;        // tile 0..31
    const int m0  = t0 * TM;
    unsigned short* rowdst = Hpack + (size_t)t0 * REGION;

    #pragma unroll
    for (int it = 0; it < 16; ++it) {
        int idx = tid + 256 * it;      // 128 rows x 32 float4 chunks
        int row = idx >> 5;
        int c4  = (idx & 31) * 4;
        float4 v = *(const float4*)(hidden + (size_t)(m0 + row) * DIM + c4);
        ushort4 o;
        o.x = f2bf(v.x); o.y = f2bf(v.y); o.z = f2bf(v.z); o.w = f2bf(v.w);
        *(ushort4*)(rowdst + row * LSTRIDE + c4) = o;
        T[(c4 + 0) * LSTRIDE + row] = o.x;
        T[(c4 + 1) * LSTRIDE + row] = o.y;
        T[(c4 + 2) * LSTRIDE + row] = o.z;
        T[(c4 + 3) * LSTRIDE + row] = o.w;
    }
    __syncthreads();
    #pragma unroll
    for (int it = 0; it < 8; ++it) {
        int idx = tid + 256 * it;      // 128 d x 16 chunks of 8 ushorts
        int d  = idx >> 4;
        int c8 = (idx & 15) * 8;
        uint4 v = *(const uint4*)(T + d * LSTRIDE + c8);
        *(uint4*)(hbt + (size_t)d * NN + m0 + c8) = v;
    }
}

// ---- main: TN=32, Hrow-only LDS (78.8 KB -> HW fits 2 blocks/CU),
//      PV B-frags direct from hbt, double-buffered DMA,
//      lgkm-only mid barrier, direct adj loads.
//      NOTE __launch_bounds__(512,2): (512,4) makes the allocator cap at 64
//      VGPRs and spill (measured r11/r15); (512,2) caps at 128 and the HW
//      still co-schedules 2 blocks/CU when VGPR<=128 and LDS fits. ----
__global__ __launch_bounds__(512, 2) void gat_flash_kernel(
    const float* __restrict__ hidden,        // fp32 (Q only)
    const unsigned short* __restrict__ Hpack,// [32][REGION]
    const unsigned short* __restrict__ hbt,  // [DIM][NN] bf16 transposed
    const int*   __restrict__ adj,           // [NN][NN] int32
    const float* __restrict__ W,
    const float* __restrict__ bvec,
    float*       __restrict__ Opart,         // [512][TN][DIM]
    float*       __restrict__ lpart)         // [512][TN]
{
    __shared__ __align__(16) unsigned short HH[2][REGION];     // 69632 B
    __shared__ __align__(16) unsigned short Plc[TN * PST];     // 8704 B
    __shared__ float redsum[8][16];                            // 512 B

    const int tid  = threadIdx.x;
    const int w    = tid >> 6;
    const int lane = tid & 63;
    const int g    = lane >> 4;
    const int l15  = lane & 15;
    const int blk  = blockIdx.x;
    const int nb   = blk >> 2;         // 0..127 row-group of 32
    const int q4   = blk & 3;
    const int n0   = nb * TN;
    const int gt0  = q4 * NTILES;      // first global tile (of 32)
    const int rg   = w >> 2;           // 0/1: 16-row group
    const int ms   = w & 3;            // QK m-slice (32 wide) / PV d-quarter
    const int lofs = lane * 16;
    const float NEG = -9.0e15f;

    const float b0 = bvec[0], b1 = bvec[1], b2 = bvec[2], b3 = bvec[3];

    // ---- prologue: DMA tile 0 -> HH[0] (overlaps Q compute below) ----
    {
        const char* src = (const char*)(Hpack + (size_t)gt0 * REGION);
        char* dst = (char*)&HH[0][0];
        #pragma unroll
        for (int it = 0; it < 5; ++it) {
            int chunk = it * 8 + w;
            if (chunk < TILE_CHUNKS)
                dma16(src + chunk * 1024 + lofs, dst + chunk * 1024);
        }
    }
    // Q into HH[1] rows k*32+r (128 rows x 128 d == exactly REGION)
    {
        int qr = tid >> 2;             // 0..127 = k*32 + r
        int r  = qr & 31;
        int d0 = (tid & 3) * 32;
        const float* hrow = hidden + (size_t)(n0 + r) * DIM + d0;
        const float* wrow = W + (qr >> 5) * DIM + d0;
        unsigned short* qdst = &HH[1][qr * LSTRIDE + d0];
        #pragma unroll
        for (int c = 0; c < 8; ++c) {
            float4 hv = *(const float4*)(hrow + 4 * c);
            float4 wv = *(const float4*)(wrow + 4 * c);
            ushort4 o;
            o.x = f2bf(hv.x * wv.x); o.y = f2bf(hv.y * wv.y);
            o.z = f2bf(hv.z * wv.z); o.w = f2bf(hv.w * wv.w);
            *(ushort4*)(qdst + 4 * c) = o;
        }
    }
    __syncthreads();   // drains tile-0 DMA (vmcnt) + Q LDS writes (lgkm)

    // A-fragments for this wave's 16 rows; HH[1] becomes a staging buffer
    bf16x8 Af[4][4];
    #pragma unroll
    for (int k = 0; k < 4; ++k)
        #pragma unroll
        for (int ks = 0; ks < 4; ++ks)
            Af[k][ks] = *(const bf16x8*)&HH[1][(k * 32 + rg * 16 + l15) * LSTRIDE + ks * 32 + 8 * g];
    __syncthreads();   // Af reads drained before tile-1 DMA may write HH[1]

    float lrow[4] = {0.f, 0.f, 0.f, 0.f};
    f32x4 Oacc[2];
    Oacc[0] = (f32x4){0.f, 0.f, 0.f, 0.f};
    Oacc[1] = (f32x4){0.f, 0.f, 0.f, 0.f};

    // direct adj codes for tile 0: 8 coalesced int loads/lane
    const size_t arow = (size_t)(n0 + rg * 16 + 4 * g) * NN;   // row of t=0
    int avc[8], avn[8];
    #pragma unroll
    for (int ch = 0; ch < 2; ++ch)
        #pragma unroll
        for (int t = 0; t < 4; ++t)
            avc[ch * 4 + t] = adj[arow + (size_t)t * NN + gt0 * TM + ms * 32 + ch * 16 + l15];

    for (int tile = 0; tile < NTILES; ++tile) {
        const int cur = tile & 1;
        const int nxt = cur ^ 1;
        const int mt0 = (gt0 + tile) * TM;

        // ---- issue next-tile DMA + adj prefetch; stays in flight all tile ----
        if (tile + 1 < NTILES) {
            const char* src = (const char*)(Hpack + (size_t)(gt0 + tile + 1) * REGION);
            char* dst = (char*)&HH[nxt][0];
            #pragma unroll
            for (int it = 0; it < 5; ++it) {
                int chunk = it * 8 + w;
                if (chunk < TILE_CHUNKS)
                    dma16(src + chunk * 1024 + lofs, dst + chunk * 1024);
            }
            #pragma unroll
            for (int ch = 0; ch < 2; ++ch)
                #pragma unroll
                for (int t = 0; t < 4; ++t)
                    avn[ch * 4 + t] = adj[arow + (size_t)t * NN + (gt0 + tile + 1) * TM + ms * 32 + ch * 16 + l15];
        }

        // ---- QK: S[k][ch] over m-slice [ms*32, +32) for rows rg*16..+16 ----
        f32x4 S[4][2];
        #pragma unroll
        for (int k = 0; k < 4; ++k) {
            S[k][0] = (f32x4){0.f, 0.f, 0.f, 0.f};
            S[k][1] = (f32x4){0.f, 0.f, 0.f, 0.f};
        }
        #pragma unroll
        for (int ks = 0; ks < 4; ++ks) {
            #pragma unroll
            for (int ch = 0; ch < 2; ++ch) {
                bf16x8 B = *(const bf16x8*)&HH[cur][(ms * 32 + ch * 16 + l15) * LSTRIDE + ks * 32 + 8 * g];
                #pragma unroll
                for (int k = 0; k < 4; ++k)
                    S[k][ch] = __builtin_amdgcn_mfma_f32_16x16x32_bf16(Af[k][ks], B, S[k][ch], 0, 0, 0);
            }
        }

        // ---- select + leakyrelu + exp (no-max softmax; scores bounded) ----
        #pragma unroll
        for (int ch = 0; ch < 2; ++ch) {
            #pragma unroll
            for (int t = 0; t < 4; ++t) {
                int a = avc[ch * 4 + t];
                float s = S[0][ch][t] + b0;
                s = (a == 2) ? S[1][ch][t] + b1 : s;
                s = (a == 3) ? S[2][ch][t] + b2 : s;
                s = (a == 4) ? S[3][ch][t] + b3 : s;
                float e = fmaxf(s, 0.2f * s);
                e = (a == 0) ? NEG : e;
                float p = __expf(e);           // exp(-9e15) -> exactly 0
                lrow[t] += p;
                Plc[(rg * 16 + 4 * g + t) * PST + ms * 32 + ch * 16 + l15] = f2bf(p);
            }
        }

        // ---- P-ready barrier: LDS-only drain; DMA stays in flight ----
        asm volatile("s_waitcnt lgkmcnt(0)\n\ts_barrier" ::: "memory");

        // ---- PV: rows rg*16..+16, d-quarter [ms*32, +32), K=128;
        //      B-frags loaded directly from hbt (L2-resident) ----
        #pragma unroll
        for (int c4 = 0; c4 < 4; ++c4) {
            bf16x8 Pa = *(const bf16x8*)&Plc[(rg * 16 + l15) * PST + c4 * 32 + 8 * g];
            #pragma unroll
            for (int dt = 0; dt < 2; ++dt) {
                const unsigned short* hp = hbt + (size_t)(ms * 32 + dt * 16 + l15) * NN + mt0 + c4 * 32 + 8 * g;
                bf16x8 Bv = *(const bf16x8*)hp;
                Oacc[dt] = __builtin_amdgcn_mfma_f32_16x16x32_bf16(Pa, Bv, Oacc[dt], 0, 0, 0);
            }
        }

        #pragma unroll
        for (int i = 0; i < 8; ++i) avc[i] = avn[i];
        __syncthreads();   // vmcnt(0) drain == "HH[nxt] staged"; buffer swap
    }

    // ---- epilogue ----
    #pragma unroll
    for (int t = 0; t < 4; ++t) {
        float v = lrow[t];
        v += __shfl_xor(v, 1); v += __shfl_xor(v, 2);
        v += __shfl_xor(v, 4); v += __shfl_xor(v, 8);
        if (l15 == 0) redsum[w][4 * g + t] = v;
    }
    __syncthreads();
    if (tid < 32) {
        int rgp = tid >> 4, rr = tid & 15;
        float s = redsum[rgp * 4 + 0][rr] + redsum[rgp * 4 + 1][rr]
                + redsum[rgp * 4 + 2][rr] + redsum[rgp * 4 + 3][rr];
        lpart[blk * 32 + tid] = s;
    }
    float* Ob = Opart + (size_t)blk * TN * DIM;
    #pragma unroll
    for (int dt = 0; dt < 2; ++dt)
        #pragma unroll
        for (int t = 0; t < 4; ++t)
            Ob[(rg * 16 + 4 * g + t) * DIM + ms * 32 + dt * 16 + l15] = Oacc[dt][t];
}

// ---- combine the four m-quarters ----
__global__ __launch_bounds__(256) void combine_kernel(
    const float* __restrict__ Opart, const float* __restrict__ lpart,
    float* __restrict__ out)
{
    int idx = blockIdx.x * 256 + threadIdx.x;
    int r = idx >> 7, d = idx & 127;
    int nb = r >> 5, rr = r & 31;
    float O = 0.f, l = 0.f;
    #pragma unroll
    for (int q = 0; q < NSPLIT; ++q) {
        O += Opart[(size_t)(nb * NSPLIT + q) * (TN * DIM) + rr * 128 + d];
        l += lpart[(nb * NSPLIT + q) * 32 + rr];
    }
    out[idx] = O / l;
}

extern "C" void kernel_launch(void* const* d_in, const int* in_sizes, int n_in,
                              void* d_out, int out_size, void* d_ws, size_t ws_size,
                              hipStream_t stream) {
    const float* hidden = (const float*)d_in[0];
    const int*   adj    = (const int*)d_in[1];
    const float* W      = (const float*)d_in[2];
    const float* b      = (const float*)d_in[3];
    float* out = (float*)d_out;

    char* ws = (char*)d_ws;
    unsigned short* Hpack = (unsigned short*)ws;                 // 32*34816 = 1.09 MB
    unsigned short* hbt   = (unsigned short*)(ws + (2u << 20));  // 1 MB
    float* Opart = (float*)(ws + (4u << 20));                    // 512*32*128*4 = 8 MB
    float* lpart = (float*)(ws + (12u << 20));                   // 64 KB

    prep_pack_kernel<<<NN / TM, 256, 0, stream>>>(hidden, Hpack, hbt);
    gat_flash_kernel<<<512, 512, 0, stream>>>(hidden, Hpack, hbt, adj, W, b, Opart, lpart);
    combine_kernel<<<NN * DIM / 256, 256, 0, stream>>>(Opart, lpart, out);
}

// Round 17
// 132.817 us; speedup vs baseline: 1.5658x; 1.2081x over previous
//
#include <hip/hip_runtime.h>

#define NN 4096
#define DIM 128
#define TN 64            // q-rows per block
#define TM 128           // m-tile size
#define NSPLIT 4         // split-m factor
#define NTILES 8         // tiles per block (32 global tiles / 4)

typedef __attribute__((ext_vector_type(8))) short bf16x8;
typedef __attribute__((ext_vector_type(4))) float f32x4;

#define LSTRIDE 136                    // ushorts per row (272 B, 16B-aligned)
#define REGION  (128 * LSTRIDE)        // one layout region (34816 ushorts)
#define TILE_USH (2 * REGION)          // Hrow|Hcol per tile = 69632 B
#define TILE_CHUNKS 68                 // 69632 / 1024
#define PST 136                        // P row stride (ushorts)

__device__ inline unsigned short f2bf(float x) {
    union { float f; unsigned u; } v; v.f = x;
    unsigned r = v.u + 0x7FFFu + ((v.u >> 16) & 1u);
    return (unsigned short)(r >> 16);
}

// async global->LDS DMA, 16 B/lane, dest = wave-uniform base + lane*16
__device__ inline void dma16(const void* g, void* l) {
    __builtin_amdgcn_global_load_lds(
        (const __attribute__((address_space(1))) void*)g,
        (__attribute__((address_space(3))) void*)l,
        16, 0, 0);
}

// ---- prep (wide, 256 blocks = 32 tiles x 8 slices):
//      hidden fp32 -> Hpack[32 tiles][Hrow 128x136 | Hcol 128x136] bf16 ----
__global__ __launch_bounds__(256) void prep_pack_kernel(
    const float* __restrict__ hidden,
    unsigned short* __restrict__ Hpack)
{
    __shared__ unsigned short T[16][LSTRIDE];   // transpose slice [d][m]
    const int tid = threadIdx.x;
    const int t0  = blockIdx.x >> 3;   // tile 0..31
    const int s   = blockIdx.x & 7;    // slice 0..7
    const int m0  = t0 * TM;
    unsigned short* rowdst = Hpack + (size_t)t0 * TILE_USH;
    unsigned short* coldst = rowdst + REGION;

    // rows part: rows [16s, 16s+16) x 128 d -> rowdst
    #pragma unroll
    for (int it = 0; it < 2; ++it) {
        int idx = tid + 256 * it;      // 16 rows x 32 float4 chunks
        int row = idx >> 5;
        int c4  = (idx & 31) * 4;
        float4 v = *(const float4*)(hidden + (size_t)(m0 + 16 * s + row) * DIM + c4);
        ushort4 o;
        o.x = f2bf(v.x); o.y = f2bf(v.y); o.z = f2bf(v.z); o.w = f2bf(v.w);
        *(ushort4*)(rowdst + (16 * s + row) * LSTRIDE + c4) = o;
    }
    // cols part: d in [16s, 16s+16) x 128 m -> T (transposed)
    #pragma unroll
    for (int it = 0; it < 2; ++it) {
        int idx = tid + 256 * it;      // 128 m x 4 d-chunks of 4
        int m  = idx >> 2;
        int dc = (idx & 3) * 4;
        float4 v = *(const float4*)(hidden + (size_t)(m0 + m) * DIM + 16 * s + dc);
        T[dc + 0][m] = f2bf(v.x);
        T[dc + 1][m] = f2bf(v.y);
        T[dc + 2][m] = f2bf(v.z);
        T[dc + 3][m] = f2bf(v.w);
    }
    __syncthreads();
    {
        int d  = tid >> 4;             // 0..15
        int c8 = (tid & 15) * 8;       // m chunk of 8
        uint4 v = *(const uint4*)(&T[d][c8]);
        *(uint4*)(coldst + (16 * s + d) * LSTRIDE + c8) = v;
    }
}

// ---- main: TN=64, 8 waves = 4 row-groups x 2 slices, double-buffered DMA,
//      lgkm-only mid barrier, direct adj loads, disjoint O ownership ----
__global__ __launch_bounds__(512, 2) void gat_flash_kernel(
    const float* __restrict__ hidden,        // fp32 (Q only)
    const unsigned short* __restrict__ Hpack,
    const int*   __restrict__ adj,           // [NN][NN] int32
    const float* __restrict__ W,
    const float* __restrict__ bvec,
    float*       __restrict__ Opart,         // [256][TN][DIM]
    float*       __restrict__ lpart)         // [256][TN]
{
    __shared__ __align__(16) unsigned short HH[2][TILE_USH];   // 139264 B
    __shared__ __align__(16) unsigned short Plc[TN * PST];     // 17408 B
    __shared__ float redsum[8][16];                            // 512 B

    const int tid  = threadIdx.x;
    const int w    = tid >> 6;
    const int lane = tid & 63;
    const int g    = lane >> 4;
    const int l15  = lane & 15;
    const int blk  = blockIdx.x;
    const int nbr  = blk >> 2;         // 0..63 row-group of 64
    const int q4   = blk & 3;
    const int n0   = nbr * TN;
    const int gt0  = q4 * NTILES;      // first global tile (of 32)
    const int rg   = w >> 1;           // 0..3: 16-row group
    const int msw  = w & 1;            // 0..1: 64-wide m-slice (QK) / d-half (PV)
    const int lofs = lane * 16;
    const float NEG = -9.0e15f;

    const float b0 = bvec[0], b1 = bvec[1], b2 = bvec[2], b3 = bvec[3];

    // ---- prologue: DMA tile 0 -> HH[0] (overlaps Q compute below) ----
    {
        const char* src = (const char*)(Hpack + (size_t)gt0 * TILE_USH);
        char* dst = (char*)&HH[0][0];
        #pragma unroll
        for (int it = 0; it < 9; ++it) {
            int chunk = it * 8 + w;
            if (chunk < TILE_CHUNKS)
                dma16(src + chunk * 1024 + lofs, dst + chunk * 1024);
        }
    }
    // Q into HH[1]: 256 rows (k*64 + r) x 128 d == exactly TILE_USH
    {
        #pragma unroll
        for (int it = 0; it < 4; ++it) {
            int idx = tid + 512 * it;      // 0..2047
            int row = idx >> 3;            // 0..255 = k*64 + r
            int c16 = (idx & 7) * 16;
            int k = row >> 6, r = row & 63;
            const float* hrow = hidden + (size_t)(n0 + r) * DIM + c16;
            const float* wrow = W + k * DIM + c16;
            unsigned short* qdst = &HH[1][row * LSTRIDE + c16];
            #pragma unroll
            for (int c = 0; c < 4; ++c) {
                float4 hv = *(const float4*)(hrow + 4 * c);
                float4 wv = *(const float4*)(wrow + 4 * c);
                ushort4 o;
                o.x = f2bf(hv.x * wv.x); o.y = f2bf(hv.y * wv.y);
                o.z = f2bf(hv.z * wv.z); o.w = f2bf(hv.w * wv.w);
                *(ushort4*)(qdst + 4 * c) = o;
            }
        }
    }
    __syncthreads();   // drains tile-0 DMA (vmcnt) + Q LDS writes (lgkm)

    // A-fragments for this wave's 16 rows; HH[1] becomes a staging buffer
    bf16x8 Af[4][4];
    #pragma unroll
    for (int k = 0; k < 4; ++k)
        #pragma unroll
        for (int ks = 0; ks < 4; ++ks)
            Af[k][ks] = *(const bf16x8*)&HH[1][(k * 64 + rg * 16 + l15) * LSTRIDE + ks * 32 + 8 * g];
    __syncthreads();   // Af reads drained before tile-1 DMA may write HH[1]

    float lrow[4] = {0.f, 0.f, 0.f, 0.f};
    f32x4 Oacc[4];
    #pragma unroll
    for (int dt = 0; dt < 4; ++dt) Oacc[dt] = (f32x4){0.f, 0.f, 0.f, 0.f};

    // direct adj codes for tile 0: 16 coalesced int loads/lane
    const size_t arow = (size_t)(n0 + rg * 16 + 4 * g) * NN;   // row of t=0
    int avc[16], avn[16];
    #pragma unroll
    for (int ch = 0; ch < 4; ++ch)
        #pragma unroll
        for (int t = 0; t < 4; ++t)
            avc[ch * 4 + t] = adj[arow + (size_t)t * NN + gt0 * TM + msw * 64 + ch * 16 + l15];

    for (int tile = 0; tile < NTILES; ++tile) {
        const int cur = tile & 1;
        const int nxt = cur ^ 1;

        // ---- issue next-tile DMA + adj prefetch; stays in flight all tile ----
        if (tile + 1 < NTILES) {
            const char* src = (const char*)(Hpack + (size_t)(gt0 + tile + 1) * TILE_USH);
            char* dst = (char*)&HH[nxt][0];
            #pragma unroll
            for (int it = 0; it < 9; ++it) {
                int chunk = it * 8 + w;
                if (chunk < TILE_CHUNKS)
                    dma16(src + chunk * 1024 + lofs, dst + chunk * 1024);
            }
            #pragma unroll
            for (int ch = 0; ch < 4; ++ch)
                #pragma unroll
                for (int t = 0; t < 4; ++t)
                    avn[ch * 4 + t] = adj[arow + (size_t)t * NN + (gt0 + tile + 1) * TM + msw * 64 + ch * 16 + l15];
        }

        // ---- QK: S[k][ch] over m-slice [msw*64, +64) for rows rg*16..+16 ----
        f32x4 S[4][4];
        #pragma unroll
        for (int k = 0; k < 4; ++k)
            #pragma unroll
            for (int ch = 0; ch < 4; ++ch)
                S[k][ch] = (f32x4){0.f, 0.f, 0.f, 0.f};
        #pragma unroll
        for (int ks = 0; ks < 4; ++ks) {
            #pragma unroll
            for (int ch = 0; ch < 4; ++ch) {
                bf16x8 B = *(const bf16x8*)&HH[cur][(msw * 64 + ch * 16 + l15) * LSTRIDE + ks * 32 + 8 * g];
                #pragma unroll
                for (int k = 0; k < 4; ++k)
                    S[k][ch] = __builtin_amdgcn_mfma_f32_16x16x32_bf16(Af[k][ks], B, S[k][ch], 0, 0, 0);
            }
        }

        // ---- select + leakyrelu + exp (no-max softmax; scores bounded) ----
        #pragma unroll
        for (int ch = 0; ch < 4; ++ch) {
            #pragma unroll
            for (int t = 0; t < 4; ++t) {
                int a = avc[ch * 4 + t];
                float s = S[0][ch][t] + b0;
                s = (a == 2) ? S[1][ch][t] + b1 : s;
                s = (a == 3) ? S[2][ch][t] + b2 : s;
                s = (a == 4) ? S[3][ch][t] + b3 : s;
                float e = fmaxf(s, 0.2f * s);
                e = (a == 0) ? NEG : e;
                float p = __expf(e);           // exp(-9e15) -> exactly 0
                lrow[t] += p;
                Plc[(rg * 16 + 4 * g + t) * PST + msw * 64 + ch * 16 + l15] = f2bf(p);
            }
        }

        // ---- P-ready barrier: LDS-only drain; DMA stays in flight ----
        asm volatile("s_waitcnt lgkmcnt(0)\n\ts_barrier" ::: "memory");

        // ---- PV: rows rg*16..+16, d-half [msw*64, +64), K=128 ----
        #pragma unroll
        for (int c4 = 0; c4 < 4; ++c4) {
            bf16x8 Pa = *(const bf16x8*)&Plc[(rg * 16 + l15) * PST + c4 * 32 + 8 * g];
            #pragma unroll
            for (int dt = 0; dt < 4; ++dt) {
                bf16x8 Bv = *(const bf16x8*)&HH[cur][REGION + (msw * 64 + dt * 16 + l15) * LSTRIDE + c4 * 32 + 8 * g];
                Oacc[dt] = __builtin_amdgcn_mfma_f32_16x16x32_bf16(Pa, Bv, Oacc[dt], 0, 0, 0);
            }
        }

        #pragma unroll
        for (int i = 0; i < 16; ++i) avc[i] = avn[i];
        __syncthreads();   // vmcnt(0) drain == "HH[nxt] staged"; buffer swap
    }

    // ---- epilogue: O is wave-disjoint (rg, msw) -> direct store ----
    #pragma unroll
    for (int t = 0; t < 4; ++t) {
        float v = lrow[t];
        v += __shfl_xor(v, 1); v += __shfl_xor(v, 2);
        v += __shfl_xor(v, 4); v += __shfl_xor(v, 8);
        if (l15 == 0) redsum[w][4 * g + t] = v;
    }
    __syncthreads();
    if (tid < TN) {
        int rg2 = tid >> 4, rr = tid & 15;
        lpart[blk * TN + tid] = redsum[rg2 * 2 + 0][rr] + redsum[rg2 * 2 + 1][rr];
    }
    float* Ob = Opart + (size_t)blk * (TN * DIM);
    #pragma unroll
    for (int dt = 0; dt < 4; ++dt)
        #pragma unroll
        for (int t = 0; t < 4; ++t)
            Ob[(rg * 16 + 4 * g + t) * DIM + msw * 64 + dt * 16 + l15] = Oacc[dt][t];
}

// ---- combine the four m-quarters ----
__global__ __launch_bounds__(256) void combine_kernel(
    const float* __restrict__ Opart, const float* __restrict__ lpart,
    float* __restrict__ out)
{
    int idx = blockIdx.x * 256 + threadIdx.x;
    int r = idx >> 7, d = idx & 127;
    int nbr = r >> 6, rr = r & 63;
    float O = 0.f, l = 0.f;
    #pragma unroll
    for (int q = 0; q < NSPLIT; ++q) {
        O += Opart[(size_t)(nbr * NSPLIT + q) * (TN * DIM) + rr * 128 + d];
        l += lpart[(nbr * NSPLIT + q) * TN + rr];
    }
    out[idx] = O / l;
}

extern "C" void kernel_launch(void* const* d_in, const int* in_sizes, int n_in,
                              void* d_out, int out_size, void* d_ws, size_t ws_size,
                              hipStream_t stream) {
    const float* hidden = (const float*)d_in[0];
    const int*   adj    = (const int*)d_in[1];
    const float* W      = (const float*)d_in[2];
    const float* b      = (const float*)d_in[3];
    float* out = (float*)d_out;

    char* ws = (char*)d_ws;
    unsigned short* Hpack = (unsigned short*)ws;                 // 2.18 MB
    float* Opart = (float*)(ws + (4u << 20));                    // 256*64*128*4 = 8 MB
    float* lpart = (float*)(ws + (12u << 20));                   // 64 KB

    prep_pack_kernel<<<(NN / TM) * 8, 256, 0, stream>>>(hidden, Hpack);
    gat_flash_kernel<<<256, 512, 0, stream>>>(hidden, Hpack, adj, W, b, Opart, lpart);
    combine_kernel<<<NN * DIM / 256, 256, 0, stream>>>(Opart, lpart, out);
}